// Round 1
// baseline (1974.116 us; speedup 1.0000x reference)
//
#include <hip/hip_runtime.h>
#include <stdint.h>

#define NTAP 27
#define C 128          // CIN == COUT == 128
#define TP 64          // points per block in main kernel
#define ACC_STRIDE 129 // +1 padding to avoid LDS bank conflicts in LN phase

__device__ __forceinline__ float bf2f(uint32_t h) {
    union { uint32_t u; float f; } v; v.u = h << 16; return v.f;
}
__device__ __forceinline__ uint32_t f2bf(float f) {
    union { float f; uint32_t u; } v; v.f = f;
    uint32_t u = v.u;
    return (u + 0x7FFFu + ((u >> 16) & 1u)) >> 16;  // round-to-nearest-even
}

// ---------------- prep kernels ----------------

__global__ void k_codes(const int* __restrict__ pts, int* __restrict__ codes, int n, int r) {
    int i = blockIdx.x * blockDim.x + threadIdx.x;
    if (i < n) {
        int p0 = pts[i * 3 + 0], p1 = pts[i * 3 + 1], p2 = pts[i * 3 + 2];
        codes[i] = (p0 * r + p1) * r + p2;
    }
}

// wp[((k*64)+cih)*128 + co] = pack(bf16(W[k][2cih][co]), bf16(W[k][2cih+1][co]))
__global__ void k_wconv(const float* __restrict__ w, uint32_t* __restrict__ wp) {
    int idx = blockIdx.x * blockDim.x + threadIdx.x;
    const int total = NTAP * (C / 2) * C;
    if (idx < total) {
        int co  = idx & (C - 1);
        int cih = (idx >> 7) & 63;
        int k   = idx >> 13;
        float w0 = w[(k * C + 2 * cih) * C + co];
        float w1 = w[(k * C + 2 * cih + 1) * C + co];
        wp[idx] = f2bf(w0) | (f2bf(w1) << 16);
    }
}

__global__ void k_table(const int* __restrict__ codes, int* __restrict__ table, int n) {
    int i = blockIdx.x * blockDim.x + threadIdx.x;
    if (i < n) table[codes[i]] = i + 1;
}

// ---------------- main fused kernel ----------------
// block = 128 threads (thread == output channel), handles TP=64 consecutive points.
// accL in LDS (fp32), compacted per-tap pair lists, fused LeakyReLU+LayerNorm.

template <bool USE_TABLE>
__global__ __launch_bounds__(128) void k_main(
    const int* __restrict__ pts, const float* __restrict__ x,
    const int* __restrict__ kv, const uint32_t* __restrict__ wp,
    const float* __restrict__ bias, const float* __restrict__ gamma,
    const float* __restrict__ beta, const int* __restrict__ codes,
    const int* __restrict__ table, float* __restrict__ out,
    int n, int r)
{
    __shared__ float accL[TP * ACC_STRIDE];   // 33.0 KB
    __shared__ float xv[8][C];                // 4 KB gather staging
    __shared__ int   jl[NTAP][TP];            // packed (t<<24)|j  (j < 2^24)
    __shared__ int   cnt[NTAP];
    __shared__ float mr[TP][2];               // mean, rstd per row

    const int tid  = threadIdx.x;
    const int base = blockIdx.x * TP;

    if (tid < NTAP) cnt[tid] = 0;
    float bv = bias[tid];
    for (int t = 0; t < TP; ++t) accL[t * ACC_STRIDE + tid] = bv;
    __syncthreads();

    // ---- phase 1: neighbor lookup + compaction for the 26 non-center taps ----
    for (int s = tid; s < TP * NTAP; s += 128) {
        int t = s & (TP - 1);
        int k = s >> 6;              // TP == 64
        if (k == 13) continue;       // center tap handled densely below
        int gp = base + t;
        if (gp >= n) continue;
        int p0 = pts[gp * 3 + 0], p1 = pts[gp * 3 + 1], p2 = pts[gp * 3 + 2];
        int q0 = p0 + kv[k * 3 + 0];
        int q1 = p1 + kv[k * 3 + 1];
        int q2 = p2 + kv[k * 3 + 2];
        if (q0 < 0 || q0 >= r || q1 < 0 || q1 >= r || q2 < 0 || q2 >= r) continue;
        int qc = (q0 * r + q1) * r + q2;
        int j = -1;
        if (USE_TABLE) {
            int v = table[qc];
            if (v >= 1 && v <= n && codes[v - 1] == qc) j = v - 1;  // verify vs garbage ws
        } else {
            int lo = 0, hi = n;
            while (lo < hi) { int mid = (lo + hi) >> 1; if (codes[mid] < qc) lo = mid + 1; else hi = mid; }
            if (lo < n && codes[lo] == qc) j = lo;
        }
        if (j >= 0) {
            int pos = atomicAdd(&cnt[k], 1);
            jl[k][pos] = j | (t << 24);
        }
    }
    __syncthreads();

    // ---- phase 2a: center tap (identity neighbor), 8-row batches ----
    for (int g = 0; g < TP; g += 8) {
        #pragma unroll
        for (int u = 0; u < 8; ++u) {
            int gp = base + g + u;
            xv[u][tid] = (gp < n) ? x[(size_t)gp * C + tid] : 0.f;
        }
        __syncthreads();
        float part[8] = {0.f, 0.f, 0.f, 0.f, 0.f, 0.f, 0.f, 0.f};
        const uint32_t* wk = wp + 13 * (C / 2) * C;
        #pragma unroll 4
        for (int cih = 0; cih < C / 2; ++cih) {
            uint32_t wpk = wk[cih * C + tid];
            float w0 = bf2f(wpk & 0xFFFFu);
            float w1 = bf2f(wpk >> 16);
            #pragma unroll
            for (int u = 0; u < 8; ++u) {
                float2 xa = ((const float2*)xv[u])[cih];
                part[u] += w0 * xa.x + w1 * xa.y;
            }
        }
        #pragma unroll
        for (int u = 0; u < 8; ++u)
            accL[(g + u) * ACC_STRIDE + tid] += part[u];
        __syncthreads();
    }

    // ---- phase 2b: sparse taps, 2-row batches ----
    for (int k = 0; k < NTAP; ++k) {
        if (k == 13) continue;
        int c = cnt[k];
        for (int g = 0; g < c; g += 2) {
            int e0 = jl[k][g];
            xv[0][tid] = x[(size_t)(e0 & 0xFFFFFF) * C + tid];
            int  e1   = 0;
            bool has1 = (g + 1 < c);
            if (has1) { e1 = jl[k][g + 1]; xv[1][tid] = x[(size_t)(e1 & 0xFFFFFF) * C + tid]; }
            else      { xv[1][tid] = 0.f; }
            __syncthreads();
            float pa0 = 0.f, pa1 = 0.f;
            const uint32_t* wk = wp + k * (C / 2) * C;
            #pragma unroll 4
            for (int cih = 0; cih < C / 2; ++cih) {
                uint32_t wpk = wk[cih * C + tid];
                float w0 = bf2f(wpk & 0xFFFFu);
                float w1 = bf2f(wpk >> 16);
                float2 xa = ((const float2*)xv[0])[cih];
                float2 xb = ((const float2*)xv[1])[cih];
                pa0 += w0 * xa.x + w1 * xa.y;
                pa1 += w0 * xb.x + w1 * xb.y;
            }
            accL[(e0 >> 24) * ACC_STRIDE + tid] += pa0;
            if (has1) accL[(e1 >> 24) * ACC_STRIDE + tid] += pa1;
            __syncthreads();
        }
    }
    __syncthreads();

    // ---- phase 3: LeakyReLU + LayerNorm stats (2 threads per row) ----
    {
        int rrow = tid >> 1, h = tid & 1;
        const float* arow = &accL[rrow * ACC_STRIDE + h * 64];
        float s1 = 0.f, s2 = 0.f;
        for (int c2 = 0; c2 < 64; ++c2) {
            float a = arow[c2];
            float v = (a >= 0.f) ? a : 0.2f * a;
            s1 += v; s2 += v * v;
        }
        s1 += __shfl_xor(s1, 1);
        s2 += __shfl_xor(s2, 1);
        float mean = s1 * (1.f / 128.f);
        float var  = s2 * (1.f / 128.f) - mean * mean;
        float rstd = rsqrtf(var + 1e-5f);
        mr[rrow][0] = mean;
        mr[rrow][1] = rstd;
    }
    __syncthreads();

    // ---- phase 4: normalize + write ----
    float gm = gamma[tid], bt = beta[tid];
    for (int t = 0; t < TP; ++t) {
        int gp = base + t;
        if (gp >= n) break;
        float a = accL[t * ACC_STRIDE + tid];
        float v = (a >= 0.f) ? a : 0.2f * a;
        float o = (v - mr[t][0]) * mr[t][1] * gm + bt;
        out[(size_t)gp * C + tid] = o;
    }
}

// ---------------- host launcher ----------------

extern "C" void kernel_launch(void* const* d_in, const int* in_sizes, int n_in,
                              void* d_out, int out_size, void* d_ws, size_t ws_size,
                              hipStream_t stream) {
    const int*   pts   = (const int*)d_in[1];
    const float* x     = (const float*)d_in[5];
    const int*   kv    = (const int*)d_in[6];
    const float* w     = (const float*)d_in[7];
    const float* bias  = (const float*)d_in[8];
    const float* gamma = (const float*)d_in[9];
    const float* beta  = (const float*)d_in[10];
    float*       out   = (float*)d_out;

    int n     = in_sizes[1] / 3;
    int level = in_sizes[3] / 2 - 2;   // pyramids has 2*(level+2) elements
    int r     = 1 << level;
    size_t r3 = (size_t)r * r * r;

    char* wsb = (char*)d_ws;
    int* codes = (int*)wsb;
    size_t codes_bytes = (((size_t)n * 4) + 255) & ~(size_t)255;
    uint32_t* wp = (uint32_t*)(wsb + codes_bytes);
    size_t wp_bytes = ((size_t)NTAP * (C / 2) * C * 4 + 255) & ~(size_t)255;
    size_t fixed_end = codes_bytes + wp_bytes;
    int* table = (int*)(wsb + fixed_end);
    bool use_table = (ws_size >= fixed_end + r3 * 4);

    k_codes<<<(n + 255) / 256, 256, 0, stream>>>(pts, codes, n, r);
    k_wconv<<<(NTAP * (C / 2) * C + 255) / 256, 256, 0, stream>>>(w, wp);

    int nb = (n + TP - 1) / TP;
    if (use_table) {
        k_table<<<(n + 255) / 256, 256, 0, stream>>>(codes, table, n);
        k_main<true><<<nb, 128, 0, stream>>>(pts, x, kv, wp, bias, gamma, beta,
                                             codes, table, out, n, r);
    } else {
        k_main<false><<<nb, 128, 0, stream>>>(pts, x, kv, wp, bias, gamma, beta,
                                              codes, (const int*)nullptr, out, n, r);
    }
}

// Round 3
// 760.093 us; speedup vs baseline: 2.5972x; 2.5972x over previous
//
#include <hip/hip_runtime.h>
#include <stdint.h>

typedef __attribute__((ext_vector_type(4))) float   f32x4;
typedef __attribute__((ext_vector_type(8))) short   short8;
typedef __attribute__((ext_vector_type(2))) uint32_t u32x2;

#define NTAP 27
#define C 128
#define PB 128          // points per block
#define NW 8            // waves per block (512 threads)

__device__ __forceinline__ uint32_t f2bf(float f) {
    union { float f; uint32_t u; } v; v.f = f;
    uint32_t u = v.u;
    return (u + 0x7FFFu + ((u >> 16) & 1u)) >> 16;  // RNE
}

// ---------------- prep kernels ----------------

__global__ void k_codes(const int* __restrict__ pts, int* __restrict__ codes, int n, int r) {
    int i = blockIdx.x * blockDim.x + threadIdx.x;
    if (i < n) codes[i] = (pts[i*3] * r + pts[i*3+1]) * r + pts[i*3+2];
}

__global__ void k_table(const int* __restrict__ pts, int* __restrict__ table, int n, int r) {
    int i = blockIdx.x * blockDim.x + threadIdx.x;
    if (i < n) {
        int code = (pts[i*3] * r + pts[i*3+1]) * r + pts[i*3+2];
        table[code] = i + 1;
    }
}

// Pre-shuffle W into exact MFMA B-fragment order.
// Frag (k, ks, cb): 256 u32; lane l dword d packs W[ci][co], W[ci+1][co]
// with co = cb*16 + (l&15), ci = ks*32 + (l>>4)*8 + 2d.
__global__ void k_wconv(const float* __restrict__ w, uint32_t* __restrict__ wpf) {
    int idx = blockIdx.x * blockDim.x + threadIdx.x;
    const int total = NTAP * 4 * 8 * 64 * 4;
    if (idx >= total) return;
    int d  = idx & 3;
    int l  = (idx >> 2) & 63;
    int cb = (idx >> 8) & 7;
    int ks = (idx >> 11) & 3;
    int k  = idx >> 13;
    int co = cb * 16 + (l & 15);
    int ci = ks * 32 + (l >> 4) * 8 + d * 2;
    float w0 = w[((size_t)k * C + ci) * C + co];
    float w1 = w[((size_t)k * C + ci + 1) * C + co];
    wpf[idx] = f2bf(w0) | (f2bf(w1) << 16);
}

// ---------------- main fused kernel ----------------
// 512 threads = 8 waves; wave w owns output cols [w*16, w*16+16).
// acc[8] f32x4 = 128 rows x 16 cols per wave (D layout: col=l&15, row=(l>>4)*4+reg).

template <bool USE_TABLE>
__global__ __launch_bounds__(512, 4) void k_main(
    const int* __restrict__ pts, const float* __restrict__ x,
    const uint32_t* __restrict__ wpf, const float* __restrict__ bias,
    const float* __restrict__ gamma, const float* __restrict__ beta,
    const int* __restrict__ table, const int* __restrict__ codes,
    float* __restrict__ out, int n, int r)
{
    __shared__ int   jtab[NTAP][PB];        // j+1, 0 = invalid   (13.8 KB)
    __shared__ int   anyv[NTAP][8];         // per (tap, mtile) any-valid
    __shared__ uint4 abuf_[16 * 256 / 16];  // 16-row A tile, swizzled (4 KB)
    __shared__ float p1s[PB][NW];           // LN partial sums (4 KB)
    __shared__ float p2s[PB][NW];           // (4 KB)
    __shared__ float2 mr[PB];               // mean, rstd

    char* ab = (char*)abuf_;
    const int tid  = threadIdx.x;
    const int w    = tid >> 6;
    const int l    = tid & 63;
    const int base = blockIdx.x * PB;

    for (int i = tid; i < NTAP * PB; i += 512) ((int*)jtab)[i] = 0;
    __syncthreads();

    // center tap: identity neighbor
    if (tid < PB) jtab[13][tid] = (base + tid < n) ? (base + tid + 1) : 0;

    // ---- phase 1: lookups, 9 (dx,dy) groups x 3 adjacent z-codes ----
    for (int s = tid; s < 9 * PB; s += 512) {
        int g = s >> 7, t = s & (PB - 1);
        int gp = base + t;
        if (gp >= n) continue;
        int pa = pts[gp*3], pb = pts[gp*3+1], pc = pts[gp*3+2];
        int dx = g / 3 - 1, dy = g % 3 - 1;
        int q0 = pa + dx, q1 = pb + dy;
        if (q0 < 0 || q0 >= r || q1 < 0 || q1 >= r) continue;
        int qbase = (q0 * r + q1) * r + pc;
        #pragma unroll
        for (int dz = -1; dz <= 1; ++dz) {
            int k = g * 3 + dz + 1;
            if (k == 13) continue;
            int q2 = pc + dz;
            if (q2 < 0 || q2 >= r) continue;
            int qc = qbase + dz;
            int j1 = 0;
            if (USE_TABLE) {
                int v = table[qc];               // poison 0xAA.. is negative
                if (v >= 1 && v <= n) j1 = v;    // written entries always valid
            } else {
                int lo = 0, hi = n;
                while (lo < hi) { int mid = (lo + hi) >> 1; if (codes[mid] < qc) lo = mid + 1; else hi = mid; }
                if (lo < n && codes[lo] == qc) j1 = lo + 1;
            }
            if (j1) jtab[k][t] = j1;
        }
    }
    __syncthreads();

    for (int s = tid; s < NTAP * 8; s += 512) {
        int k = s >> 3, mt = s & 7;
        int a = 0;
        #pragma unroll
        for (int i = 0; i < 16; ++i) a |= jtab[k][mt * 16 + i];
        anyv[k][mt] = a;
    }
    __syncthreads();

    // ---- accumulators: init to bias ----
    float bv = bias[w * 16 + (l & 15)];
    f32x4 acc[8];
    #pragma unroll
    for (int mt = 0; mt < 8; ++mt) acc[mt] = (f32x4){bv, bv, bv, bv};

    const int srow = tid >> 5;      // staging: row 0..15
    const int sc4  = tid & 31;      // float4 column index
    const int swrb = srow * 256;
    const int arow = l & 15;        // A-frag row
    const int kgrp = l >> 4;

    // ---- tap loop ----
    #pragma unroll 1
    for (int k = 0; k < NTAP; ++k) {
        int anytap = 0;
        #pragma unroll
        for (int mt = 0; mt < 8; ++mt) anytap |= anyv[k][mt];
        if (!anytap) continue;

        short8 bfr[4];
        #pragma unroll
        for (int ks = 0; ks < 4; ++ks)
            bfr[ks] = *(const short8*)(wpf + ((size_t)((k * 4 + ks) * 8 + w) * 64 + l) * 4);

        #pragma unroll
        for (int mt = 0; mt < 8; ++mt) {
            if (anyv[k][mt]) {
                // stage 16 rows (gather + fp32->bf16 + XOR-swizzled LDS write)
                {
                    int jj = jtab[k][mt * 16 + srow];
                    f32x4 xv = (f32x4){0.f, 0.f, 0.f, 0.f};
                    if (jj) xv = *(const f32x4*)(x + (size_t)(jj - 1) * C + sc4 * 4);
                    uint32_t u0 = f2bf(xv.x) | (f2bf(xv.y) << 16);
                    uint32_t u1 = f2bf(xv.z) | (f2bf(xv.w) << 16);
                    int byte = swrb + ((sc4 * 8) ^ ((srow & 7) << 4));
                    *(u32x2*)(ab + byte) = (u32x2){u0, u1};
                }
                __syncthreads();
                // MFMA: 4 k-steps
                #pragma unroll
                for (int ks = 0; ks < 4; ++ks) {
                    int byte = arow * 256 + ((ks * 64 + kgrp * 16) ^ ((arow & 7) << 4));
                    short8 afr = *(const short8*)(ab + byte);
                    acc[mt] = __builtin_amdgcn_mfma_f32_16x16x32_bf16(afr, bfr[ks], acc[mt], 0, 0, 0);
                }
                __syncthreads();
            }
        }
    }

    // ---- LeakyReLU + LN partial sums (per-row, 16-lane shfl groups) ----
    #pragma unroll
    for (int mt = 0; mt < 8; ++mt) {
        #pragma unroll
        for (int rg = 0; rg < 4; ++rg) {
            float v = acc[mt][rg];
            v = (v >= 0.f) ? v : 0.2f * v;
            acc[mt][rg] = v;
            float s1 = v, s2 = v * v;
            s1 += __shfl_xor(s1, 1);  s2 += __shfl_xor(s2, 1);
            s1 += __shfl_xor(s1, 2);  s2 += __shfl_xor(s2, 2);
            s1 += __shfl_xor(s1, 4);  s2 += __shfl_xor(s2, 4);
            s1 += __shfl_xor(s1, 8);  s2 += __shfl_xor(s2, 8);
            if ((l & 15) == 0) {
                int row = mt * 16 + (l >> 4) * 4 + rg;
                p1s[row][w] = s1;
                p2s[row][w] = s2;
            }
        }
    }
    __syncthreads();
    if (tid < PB) {
        float s1 = 0.f, s2 = 0.f;
        #pragma unroll
        for (int ww = 0; ww < NW; ++ww) { s1 += p1s[tid][ww]; s2 += p2s[tid][ww]; }
        float mean = s1 * (1.f / 128.f);
        float var  = s2 * (1.f / 128.f) - mean * mean;
        mr[tid] = make_float2(mean, rsqrtf(var + 1e-5f));
    }
    __syncthreads();

    // ---- normalize + write ----
    float gm = gamma[w * 16 + (l & 15)];
    float bt = beta [w * 16 + (l & 15)];
    #pragma unroll
    for (int mt = 0; mt < 8; ++mt) {
        #pragma unroll
        for (int rg = 0; rg < 4; ++rg) {
            int row = mt * 16 + (l >> 4) * 4 + rg;
            int gp  = base + row;
            if (gp < n) {
                float2 m = mr[row];
                float o = (acc[mt][rg] - m.x) * m.y * gm + bt;
                out[(size_t)gp * C + w * 16 + (l & 15)] = o;
            }
        }
    }
}

// ---------------- host launcher ----------------

extern "C" void kernel_launch(void* const* d_in, const int* in_sizes, int n_in,
                              void* d_out, int out_size, void* d_ws, size_t ws_size,
                              hipStream_t stream) {
    const int*   pts   = (const int*)d_in[1];
    const float* x     = (const float*)d_in[5];
    const float* w     = (const float*)d_in[7];
    const float* bias  = (const float*)d_in[8];
    const float* gamma = (const float*)d_in[9];
    const float* beta  = (const float*)d_in[10];
    float*       out   = (float*)d_out;

    int n     = in_sizes[1] / 3;
    int level = in_sizes[3] / 2 - 2;     // pyramids: 2*(level+2) elems
    int r     = 1 << level;
    size_t r3 = (size_t)r * r * r;

    char* wsb = (char*)d_ws;
    uint32_t* wpf = (uint32_t*)wsb;
    size_t wp_bytes = (((size_t)NTAP * 4 * 8 * 64 * 4) * 4 + 255) & ~(size_t)255;
    int* codes = (int*)(wsb + wp_bytes);
    size_t codes_bytes = ((size_t)n * 4 + 255) & ~(size_t)255;
    int* table = (int*)(wsb + wp_bytes + codes_bytes);
    bool use_table = ws_size >= wp_bytes + codes_bytes + r3 * 4;

    const int total_w = NTAP * 4 * 8 * 64 * 4;
    k_wconv<<<(total_w + 255) / 256, 256, 0, stream>>>(w, wpf);

    int nb = (n + PB - 1) / PB;
    if (use_table) {
        k_table<<<(n + 255) / 256, 256, 0, stream>>>(pts, table, n, r);
        k_main<true><<<nb, 512, 0, stream>>>(pts, x, wpf, bias, gamma, beta,
                                             table, codes, out, n, r);
    } else {
        k_codes<<<(n + 255) / 256, 256, 0, stream>>>(pts, codes, n, r);
        k_main<false><<<nb, 512, 0, stream>>>(pts, x, wpf, bias, gamma, beta,
                                              table, codes, out, n, r);
    }
}